// Round 2
// 503.782 us; speedup vs baseline: 1.0912x; 1.0912x over previous
//
#include <hip/hip_runtime.h>

#define DD 1024
#define KK 32

// --- P0: vvinv[k] = 1 / dot(V[k], V[k]) ---------------------------------
__global__ void vv_inv_kernel(const float* __restrict__ V, float* __restrict__ vvinv) {
    int k = blockIdx.x;
    const float* v = V + k * DD;
    int t = threadIdx.x;  // 256 threads
    float s = 0.f;
    for (int i = t; i < DD; i += 256) { float x = v[i]; s += x * x; }
    #pragma unroll
    for (int off = 32; off >= 1; off >>= 1) s += __shfl_xor(s, off, 64);
    __shared__ float red[4];
    if ((t & 63) == 0) red[t >> 6] = s;
    __syncthreads();
    if (t == 0) vvinv[k] = 1.0f / (red[0] + red[1] + red[2] + red[3]);
}

// --- Main fused kernel ---------------------------------------------------
// Wave owns 4 nodes; each lane holds 16 floats/node of the row in registers.
// Lane L owns floats {8L..8L+7} u {512+8L..512+8L+7}, with a (L>>2)&1 16B
// jitter so the four 16B LDS reads per k cover all 32 banks (conflict-free).
//
// Cross-lane reduction uses the packed multi-value butterfly: the 4
// independent dots share stages. xor32 packs (d0,d2)/(d1,d3) [2 shfl],
// xor16 packs the survivors [1 shfl], xor8/4/2/1 reduce one value [4 shfl],
// then xor16 + xor32 broadcast all four totals back [3 shfl].
// 10 shuffles per k instead of 24.
__global__ __launch_bounds__(1024) void hh_tower_kernel(
    const float* __restrict__ H, const float* __restrict__ V,
    const float* __restrict__ vvinv, float* __restrict__ out, int Nn)
{
    extern __shared__ float Vl[];  // 32 x 1024 fp32 = 128 KB
    {
        const float4* src = (const float4*)V;
        float4* dst = (float4*)Vl;
        int t = threadIdx.x;
        #pragma unroll
        for (int i = 0; i < 8; ++i) dst[t + (i << 10)] = src[t + (i << 10)];
    }
    __syncthreads();

    const int lane = threadIdx.x & 63;
    const int wid  = threadIdx.x >> 6;
    const int gwave  = blockIdx.x * (blockDim.x >> 6) + wid;
    const int nwaves = gridDim.x * (blockDim.x >> 6);

    const int s  = (lane >> 2) & 1;
    const int o0 = (lane << 3) + (s << 2);        // first half, jittered
    const int o1 = (lane << 3) + ((1 - s) << 2);  // first half, complement
    const int o2 = 512 + o0;                      // second half
    const int o3 = 512 + o1;

    const bool b5 = (lane & 32) != 0;
    const bool b4 = (lane & 16) != 0;

    const int ngroups = Nn >> 2;
    for (int g = gwave; g < ngroups; g += nwaves) {
        const int base = g << 2;
        float4 h0[4], h1[4], h2[4], h3[4];
        #pragma unroll
        for (int m = 0; m < 4; ++m) {
            const float* row = H + (size_t)(base + m) * DD;
            h0[m] = *(const float4*)(row + o0);
            h1[m] = *(const float4*)(row + o1);
            h2[m] = *(const float4*)(row + o2);
            h3[m] = *(const float4*)(row + o3);
        }

        #pragma unroll 2
        for (int k = 0; k < KK; ++k) {
            const float* vr = Vl + (k << 10);
            const float4 v0 = *(const float4*)(vr + o0);
            const float4 v1 = *(const float4*)(vr + o1);
            const float4 v2 = *(const float4*)(vr + o2);
            const float4 v3 = *(const float4*)(vr + o3);
            const float vi = vvinv[k];

            float dot[4];
            #pragma unroll
            for (int m = 0; m < 4; ++m) {
                float pa = h0[m].x * v0.x + h0[m].y * v0.y + h0[m].z * v0.z + h0[m].w * v0.w;
                float pb = h1[m].x * v1.x + h1[m].y * v1.y + h1[m].z * v1.z + h1[m].w * v1.w;
                float pc = h2[m].x * v2.x + h2[m].y * v2.y + h2[m].z * v2.z + h2[m].w * v2.w;
                float pd = h3[m].x * v3.x + h3[m].y * v3.y + h3[m].z * v3.z + h3[m].w * v3.w;
                dot[m] = (pa + pb) + (pc + pd);
            }

            // ---- packed 64-lane all-reduce of 4 values, 10 shuffles ----
            // Stage 1 (xor32): keep-side gets pair-sum; b5=0 keeps d0,d1; b5=1 keeps d2,d3.
            float s02 = b5 ? dot[2] : dot[0];
            float t02 = b5 ? dot[0] : dot[2];
            s02 += __shfl_xor(t02, 32, 64);
            float s13 = b5 ? dot[3] : dot[1];
            float t13 = b5 ? dot[1] : dot[3];
            s13 += __shfl_xor(t13, 32, 64);
            // Stage 2 (xor16): b4=0 keeps s02-line, b4=1 keeps s13-line.
            float f = b4 ? s13 : s02;
            float t = b4 ? s02 : s13;
            f += __shfl_xor(t, 16, 64);
            // group (b5,b4) = (0,0)->d0, (0,1)->d1, (1,0)->d2, (1,1)->d3
            // Stages 3-6: single-value butterfly over remaining 16-lane span.
            f += __shfl_xor(f, 8, 64);
            f += __shfl_xor(f, 4, 64);
            f += __shfl_xor(f, 2, 64);
            f += __shfl_xor(f, 1, 64);
            // f = full 64-lane sum of this group's dot.
            // Stage 7 (xor16): fetch sibling value within this half.
            float gq = __shfl_xor(f, 16, 64);
            float x0 = b4 ? gq : f;    // b5=0: D0 ; b5=1: D2
            float x1 = b4 ? f : gq;    // b5=0: D1 ; b5=1: D3
            // Stage 8 (xor32): exchange both with the other half.
            float y0 = __shfl_xor(x0, 32, 64);
            float y1 = __shfl_xor(x1, 32, 64);
            float gc[4];
            gc[0] = (b5 ? y0 : x0) * vi;
            gc[1] = (b5 ? y1 : x1) * vi;
            gc[2] = (b5 ? x0 : y0) * vi;
            gc[3] = (b5 ? x1 : y1) * vi;

            #pragma unroll
            for (int m = 0; m < 4; ++m) {
                const float c = gc[m];
                h0[m].x -= c * v0.x; h0[m].y -= c * v0.y; h0[m].z -= c * v0.z; h0[m].w -= c * v0.w;
                h1[m].x -= c * v1.x; h1[m].y -= c * v1.y; h1[m].z -= c * v1.z; h1[m].w -= c * v1.w;
                h2[m].x -= c * v2.x; h2[m].y -= c * v2.y; h2[m].z -= c * v2.z; h2[m].w -= c * v2.w;
                h3[m].x -= c * v3.x; h3[m].y -= c * v3.y; h3[m].z -= c * v3.z; h3[m].w -= c * v3.w;
            }
        }

        #pragma unroll
        for (int m = 0; m < 4; ++m) {
            float* row = out + (size_t)(base + m) * DD;
            *(float4*)(row + o0) = h0[m];
            *(float4*)(row + o1) = h1[m];
            *(float4*)(row + o2) = h2[m];
            *(float4*)(row + o3) = h3[m];
        }
    }
}

extern "C" void kernel_launch(void* const* d_in, const int* in_sizes, int n_in,
                              void* d_out, int out_size, void* d_ws, size_t ws_size,
                              hipStream_t stream) {
    const float* H = (const float*)d_in[0];   // node_feat [N, 1024] fp32
    const float* V = (const float*)d_in[1];   // V [32, 1024] fp32
    float* vvinv = (float*)d_ws;              // 32 floats scratch
    float* out = (float*)d_out;
    int Nn = in_sizes[0] / DD;                // 65536

    vv_inv_kernel<<<KK, 256, 0, stream>>>(V, vvinv);

    const int smem = KK * DD * (int)sizeof(float);  // 128 KB
    hipFuncSetAttribute((const void*)hh_tower_kernel,
                        hipFuncAttributeMaxDynamicSharedMemorySize, smem);
    hh_tower_kernel<<<256, 1024, smem, stream>>>(H, V, vvinv, out, Nn);
}